// Round 9
// baseline (36105.008 us; speedup 1.0000x reference)
//
#include <hip/hip_runtime.h>
#include <hip/hip_fp16.h>

// LSTMTrajectoryEncoder on MI355X.
// Phase 0: compact_kernel — pos[t] = exclusive prefix of mask (masked LSTM
//   steps are exact carry no-ops and are skipped entirely).
// Phase 1: zx_kernel — zx row for active step t written DIRECTLY to compacted
//   slot pos[t] (f16, permuted [slot][4*unit+gate]). Scan reads linearly.
// Phase 2: scan_kernel — 512 thr = unit j (n>>2) x k-quarter r (n&3),
//   2 waves/SIMD: round-8 showed ~480 stall cyc/step of pure latency chain
//   (ds_read -> dots -> shfl -> exp/rcp -> ds_write -> barrier) that one
//   wave/SIMD cannot hide; the second wave's issue fills those gaps.
//   Wh slice (4 gates x 32 k) = 64 packed-f16 half2 regs, v_dot2_f32_f16,
//   2-round butterfly, rcp gates, lgkmcnt-only barrier, 2-step unroll with
//   2-deep register prefetch of the linear zc stream.

#define TT   65536
#define DINN 128
#define HH   128
#define G4   512     // 4*H
#define NEG  0.01f
#define ROWS 16      // t-rows per GEMM block
#define CTH  1024    // compaction threads

typedef _Float16 half2_t __attribute__((ext_vector_type(2)));

#if defined(__has_builtin)
#if __has_builtin(__builtin_amdgcn_fdot2)
#define FDOT2(a, b, c) __builtin_amdgcn_fdot2((a), (b), (c), false)
#endif
#if __has_builtin(__builtin_amdgcn_rcpf)
#define RCPF(x) __builtin_amdgcn_rcpf(x)
#endif
#endif
#ifndef FDOT2
__device__ __forceinline__ float fdot2_sw(half2_t a, half2_t b, float c) {
    return c + (float)a[0] * (float)b[0] + (float)a[1] * (float)b[1];
}
#define FDOT2(a, b, c) fdot2_sw((a), (b), (c))
#endif
#ifndef RCPF
#define RCPF(x) (1.0f / (x))
#endif

// LDS-only barrier: waits DS ops, leaves global loads in flight (no vmcnt drain)
#define LDS_BARRIER() asm volatile("s_waitcnt lgkmcnt(0)\n\ts_barrier" ::: "memory")

// ---------------------------------------------------------- compaction kernel
__global__ __launch_bounds__(CTH) void compact_kernel(
    const int* __restrict__ mask, int* __restrict__ pos, int* __restrict__ cnt_out)
{
    __shared__ int sc[CTH];
    const int th   = threadIdx.x;
    const int base = th * (TT / CTH);
    int cnt = 0;
    #pragma unroll 8
    for (int k = 0; k < TT / CTH; ++k) cnt += (mask[base + k] != 0);
    sc[th] = cnt;
    __syncthreads();
    for (int off = 1; off < CTH; off <<= 1) {      // inclusive Hillis-Steele
        int v = sc[th];
        int u = (th >= off) ? sc[th - off] : 0;
        __syncthreads();
        sc[th] = v + u;
        __syncthreads();
    }
    int p = sc[th] - cnt;                          // exclusive prefix
    for (int k = 0; k < TT / CTH; ++k) {
        int t = base + k;
        pos[t] = p;
        p += (mask[t] != 0);
    }
    if (th == CTH - 1) cnt_out[0] = sc[CTH - 1];
}

// ---------------------------------------------------------------- GEMM kernel
__global__ __launch_bounds__(512) void zx_kernel(
    const float* __restrict__ x, const float* __restrict__ W_in,
    const float* __restrict__ b_in, const float* __restrict__ Wi,
    const float* __restrict__ b_lstm, const int* __restrict__ mask,
    const int* __restrict__ pos, __half* __restrict__ zc)
{
    __shared__ float xt[ROWS][DINN];
    __shared__ float xp[ROWS][DINN];
    const int tid = threadIdx.x;
    const int t0  = blockIdx.x * ROWS;

    {
        const float4* src = (const float4*)(x + (size_t)t0 * DINN);
        ((float4*)&xt[0][0])[tid] = src[tid];
    }
    __syncthreads();

    {
        const int c  = tid & 127;
        const int r0 = tid >> 7;
        float a0 = b_in[c], a1 = a0, a2 = a0, a3 = a0;
        #pragma unroll
        for (int k4 = 0; k4 < DINN / 4; ++k4) {
            const float w0 = W_in[(k4*4+0)*DINN + c];
            const float w1 = W_in[(k4*4+1)*DINN + c];
            const float w2 = W_in[(k4*4+2)*DINN + c];
            const float w3 = W_in[(k4*4+3)*DINN + c];
            float4 v0 = *(const float4*)&xt[r0 +  0][k4*4];
            float4 v1 = *(const float4*)&xt[r0 +  4][k4*4];
            float4 v2 = *(const float4*)&xt[r0 +  8][k4*4];
            float4 v3 = *(const float4*)&xt[r0 + 12][k4*4];
            a0 += v0.x*w0 + v0.y*w1 + v0.z*w2 + v0.w*w3;
            a1 += v1.x*w0 + v1.y*w1 + v1.z*w2 + v1.w*w3;
            a2 += v2.x*w0 + v2.y*w1 + v2.z*w2 + v2.w*w3;
            a3 += v3.x*w0 + v3.y*w1 + v3.z*w2 + v3.w*w3;
        }
        xp[r0 +  0][c] = a0 >= 0.f ? a0 : NEG * a0;
        xp[r0 +  4][c] = a1 >= 0.f ? a1 : NEG * a1;
        xp[r0 +  8][c] = a2 >= 0.f ? a2 : NEG * a2;
        xp[r0 + 12][c] = a3 >= 0.f ? a3 : NEG * a3;
    }
    __syncthreads();

    {
        const int c2 = tid;
        float acc[ROWS];
        const float bl = b_lstm[c2];
        #pragma unroll
        for (int r = 0; r < ROWS; ++r) acc[r] = bl;
        #pragma unroll 4
        for (int k4 = 0; k4 < DINN / 4; ++k4) {
            const float w0 = Wi[(k4*4+0)*G4 + c2];
            const float w1 = Wi[(k4*4+1)*G4 + c2];
            const float w2 = Wi[(k4*4+2)*G4 + c2];
            const float w3 = Wi[(k4*4+3)*G4 + c2];
            #pragma unroll
            for (int r = 0; r < ROWS; ++r) {
                float4 a = *(const float4*)&xp[r][k4*4];
                acc[r] += a.x*w0 + a.y*w1 + a.z*w2 + a.w*w3;
            }
        }
        // dest layout [slot][4*unit + gate]; c2 = gate*128 + unit
        const int dst = 4 * (c2 & 127) + (c2 >> 7);
        #pragma unroll
        for (int r = 0; r < ROWS; ++r) {
            const int t = t0 + r;
            if (mask[t])
                zc[(size_t)pos[t] * G4 + dst] = __float2half(acc[r]);
        }
    }
}

// ---------------------------------------------------------------- scan kernel
// 64 packed weight regs: w<g>_<p> = half2( Wh[kb][cg], Wh[kb+1][cg] ),
// kb = 32r + 2p (p in [0,16)), cg = (g<<7)|j.
#define DW(g,p)  unsigned w##g##_##p;
#define LW(g,p)  { const int kb = (r<<5) + 2*(p); const int cg = ((g)<<7)|j; \
    half2_t v_; v_[0] = (_Float16)Wh[(kb+0)*G4 + cg];                        \
    v_[1] = (_Float16)Wh[(kb+1)*G4 + cg];                                    \
    w##g##_##p = __builtin_bit_cast(unsigned, v_); }
#define PIN(g,p) asm volatile("" : "+v"(w##g##_##p));

#define BCH(u) __builtin_bit_cast(half2_t, (u))
#define DOTP(p, hu) {                          \
    const half2_t h_ = BCH(hu);                \
    p0 = FDOT2(h_, BCH(w0##_##p), p0);         \
    p1 = FDOT2(h_, BCH(w1##_##p), p1);         \
    p2 = FDOT2(h_, BCH(w2##_##p), p2);         \
    p3 = FDOT2(h_, BCH(w3##_##p), p3); }

#define FORP(M,g) M(g,0)  M(g,1)  M(g,2)  M(g,3)  M(g,4)  M(g,5)  M(g,6)  M(g,7)  \
                  M(g,8)  M(g,9)  M(g,10) M(g,11) M(g,12) M(g,13) M(g,14) M(g,15)
#define FORALL(M) FORP(M,0) FORP(M,1) FORP(M,2) FORP(M,3)

// one LSTM step: dot from hbuf[PI], gates with ZZ, publish h to hbuf[PO]
#define STEP(ZZ, PI, PO) {                                            \
    float p0 = 0.f, p1 = 0.f, p2 = 0.f, p3 = 0.f;                     \
    const uint4* hp4 = (const uint4*)&hbuf[PI][r << 5];               \
    const uint4 ha = hp4[0], hb = hp4[1], hc = hp4[2], hd = hp4[3];   \
    DOTP(0,  ha.x) DOTP(1,  ha.y) DOTP(2,  ha.z) DOTP(3,  ha.w)      \
    DOTP(4,  hb.x) DOTP(5,  hb.y) DOTP(6,  hb.z) DOTP(7,  hb.w)      \
    DOTP(8,  hc.x) DOTP(9,  hc.y) DOTP(10, hc.z) DOTP(11, hc.w)      \
    DOTP(12, hd.x) DOTP(13, hd.y) DOTP(14, hd.z) DOTP(15, hd.w)      \
    p0 += __shfl_xor(p0, 1);                                          \
    p1 += __shfl_xor(p1, 1);                                          \
    p2 += __shfl_xor(p2, 1);                                          \
    p3 += __shfl_xor(p3, 1);                                          \
    p0 += __shfl_xor(p0, 2);                                          \
    p1 += __shfl_xor(p1, 2);                                          \
    p2 += __shfl_xor(p2, 2);                                          \
    p3 += __shfl_xor(p3, 2);                                          \
    const __half2 zlo = *(const __half2*)&(ZZ).x;                     \
    const __half2 zhi = *(const __half2*)&(ZZ).y;                     \
    const float zi = p0 + __half2float(zlo.x);                        \
    const float zf = p1 + __half2float(zlo.y);                        \
    const float zg = p2 + __half2float(zhi.x);                        \
    const float zo = p3 + __half2float(zhi.y);                        \
    const float i_s = RCPF(1.f + __expf(-zi));                        \
    const float f_s = RCPF(1.f + __expf(-zf));                        \
    const float o_s = RCPF(1.f + __expf(-zo));                        \
    const float g_t = 1.f - 2.f * RCPF(__expf(2.f * zg) + 1.f);       \
    c_st = f_s * c_st + i_s * g_t;                                    \
    const float t_c = 1.f - 2.f * RCPF(__expf(2.f * c_st) + 1.f);     \
    h_st = o_s * t_c;                                                 \
    if (r == 0) hbuf[PO][j] = __float2half(h_st);                     \
    LDS_BARRIER();                                                    \
}

__global__ __launch_bounds__(512, 2)
__attribute__((amdgpu_waves_per_eu(2, 2)))
void scan_kernel(
    const __half* __restrict__ zc, const float* __restrict__ Wh,
    const int* __restrict__ cnt, const float* __restrict__ W_lat,
    const float* __restrict__ b_lat, float* __restrict__ out)
{
    const int n = threadIdx.x;
    const int j = n >> 2;        // hidden unit
    const int r = n & 3;         // k-quarter

    FORALL(DW)       // 64 packed half2 regs
    FORALL(LW)       // load + convert f32 -> f16
    FORALL(PIN)      // pin after load (kills rematerialization)

    __shared__ __half hbuf[2][HH];
    __shared__ float  hfin[HH];
    if (n < 256) ((__half*)hbuf)[n] = __float2half(0.f);   // both buffers
    float c_st = 0.f, h_st = 0.f;
    __syncthreads();

    const int S = cnt[0];
    const uint2* prow = (const uint2*)zc + j;  // linear compacted stream
    // 2-deep register prefetch: z0/z1 hold rows i/i+1
    uint2 z0 = prow[0];
    uint2 z1 = prow[HH];
    prow += 2 * HH;

    int i = 0;
    for (; i + 1 < S; i += 2) {
        // issue prefetch for steps i+2, i+3 (first read ~2 step-bodies later)
        const uint2 za = prow[0];
        const uint2 zb = prow[HH];
        prow += 2 * HH;
        STEP(z0, 0, 1)     // step i   : read hbuf[0], write hbuf[1]
        STEP(z1, 1, 0)     // step i+1 : read hbuf[1], write hbuf[0]
        z0 = za;
        z1 = zb;
    }
    if (i < S) {           // odd tail
        STEP(z0, 0, 1)
    }

    // latent = h_f @ W_lat + b_lat  (fp32 final h for precision)
    if (r == 0) hfin[j] = h_st;
    __syncthreads();
    if (n < 16) {
        float acc = b_lat[n];
        #pragma unroll
        for (int k = 0; k < HH; ++k) acc += hfin[k] * W_lat[k * 16 + n];
        out[n] = acc;
    }
}

// ---------------------------------------------------------------- launcher
extern "C" void kernel_launch(void* const* d_in, const int* in_sizes, int n_in,
                              void* d_out, int out_size, void* d_ws, size_t ws_size,
                              hipStream_t stream) {
    const float* x      = (const float*)d_in[0];
    const int*   mask   = (const int*)  d_in[1];
    const float* W_in   = (const float*)d_in[2];
    const float* b_in   = (const float*)d_in[3];
    const float* Wi     = (const float*)d_in[4];
    const float* Wh     = (const float*)d_in[5];
    const float* b_lstm = (const float*)d_in[6];
    const float* W_lat  = (const float*)d_in[7];
    const float* b_lat  = (const float*)d_in[8];
    float* out = (float*)d_out;

    __half* zc  = (__half*)d_ws;                               // (TT+4) rows
    int*    pos = (int*)((char*)d_ws + (size_t)(TT + 4) * G4 * 2);
    int*    cnt = pos + TT;

    compact_kernel<<<1, CTH, 0, stream>>>(mask, pos, cnt);
    zx_kernel<<<TT / ROWS, 512, 0, stream>>>(x, W_in, b_in, Wi, b_lstm,
                                             mask, pos, zc);
    scan_kernel<<<1, 512, 0, stream>>>(zc, Wh, cnt, W_lat, b_lat, out);
}

// Round 10
// 27815.552 us; speedup vs baseline: 1.2980x; 1.2980x over previous
//
#include <hip/hip_runtime.h>
#include <hip/hip_fp16.h>

// LSTMTrajectoryEncoder on MI355X.
// Phase 0: compact_kernel — pos[t] = exclusive prefix of mask (masked LSTM
//   steps are exact carry no-ops and are skipped entirely).
// Phase 1: zx_kernel — zx row for active step t written DIRECTLY to compacted
//   slot pos[t] (f16, permuted [slot][4*unit+gate]). Scan reads linearly.
// Phase 2: scan_kernel (1 block, 256 thr = unit j x k-half s, 1 wave/SIMD):
//   Wh slice (4 gates x 64 k) as 128 packed-f16 half2 regs, v_dot2_f32_f16,
//   rcp gates, lgkmcnt-only barrier, 2-step unroll + register prefetch.
//   Round 10: the split-K pair reduction (lanes 2j/2j+1, intra-quad) now
//   uses DPP quad_perm(1,0,3,2) + v_add_f32 instead of __shfl_xor
//   (ds_swizzle round-trips on the serial chain), and the z input is
//   pre-loaded into the dot accumulators on lane s==0 (off-chain) instead
//   of added after the reduction (on-chain).

#define TT   65536
#define DINN 128
#define HH   128
#define G4   512     // 4*H
#define NEG  0.01f
#define ROWS 16      // t-rows per GEMM block
#define CTH  1024    // compaction threads

typedef _Float16 half2_t __attribute__((ext_vector_type(2)));

#if defined(__has_builtin)
#if __has_builtin(__builtin_amdgcn_fdot2)
#define FDOT2(a, b, c) __builtin_amdgcn_fdot2((a), (b), (c), false)
#endif
#if __has_builtin(__builtin_amdgcn_rcpf)
#define RCPF(x) __builtin_amdgcn_rcpf(x)
#endif
#endif
#ifndef FDOT2
__device__ __forceinline__ float fdot2_sw(half2_t a, half2_t b, float c) {
    return c + (float)a[0] * (float)b[0] + (float)a[1] * (float)b[1];
}
#define FDOT2(a, b, c) fdot2_sw((a), (b), (c))
#endif
#ifndef RCPF
#define RCPF(x) (1.0f / (x))
#endif

// LDS-only barrier: waits DS ops, leaves global loads in flight (no vmcnt drain)
#define LDS_BARRIER() asm volatile("s_waitcnt lgkmcnt(0)\n\ts_barrier" ::: "memory")

// pair-sum via DPP quad_perm([1,0,3,2]) — pure VALU, no LDS pipe
__device__ __forceinline__ float xor1_add(float x) {
    int t = __builtin_amdgcn_update_dpp(0, __builtin_bit_cast(int, x),
                                        0xB1, 0xF, 0xF, true);
    return x + __builtin_bit_cast(float, t);
}

// ---------------------------------------------------------- compaction kernel
__global__ __launch_bounds__(CTH) void compact_kernel(
    const int* __restrict__ mask, int* __restrict__ pos, int* __restrict__ cnt_out)
{
    __shared__ int sc[CTH];
    const int th   = threadIdx.x;
    const int base = th * (TT / CTH);
    int cnt = 0;
    #pragma unroll 8
    for (int k = 0; k < TT / CTH; ++k) cnt += (mask[base + k] != 0);
    sc[th] = cnt;
    __syncthreads();
    for (int off = 1; off < CTH; off <<= 1) {      // inclusive Hillis-Steele
        int v = sc[th];
        int u = (th >= off) ? sc[th - off] : 0;
        __syncthreads();
        sc[th] = v + u;
        __syncthreads();
    }
    int p = sc[th] - cnt;                          // exclusive prefix
    for (int k = 0; k < TT / CTH; ++k) {
        int t = base + k;
        pos[t] = p;
        p += (mask[t] != 0);
    }
    if (th == CTH - 1) cnt_out[0] = sc[CTH - 1];
}

// ---------------------------------------------------------------- GEMM kernel
__global__ __launch_bounds__(512) void zx_kernel(
    const float* __restrict__ x, const float* __restrict__ W_in,
    const float* __restrict__ b_in, const float* __restrict__ Wi,
    const float* __restrict__ b_lstm, const int* __restrict__ mask,
    const int* __restrict__ pos, __half* __restrict__ zc)
{
    __shared__ float xt[ROWS][DINN];
    __shared__ float xp[ROWS][DINN];
    const int tid = threadIdx.x;
    const int t0  = blockIdx.x * ROWS;

    {
        const float4* src = (const float4*)(x + (size_t)t0 * DINN);
        ((float4*)&xt[0][0])[tid] = src[tid];
    }
    __syncthreads();

    {
        const int c  = tid & 127;
        const int r0 = tid >> 7;
        float a0 = b_in[c], a1 = a0, a2 = a0, a3 = a0;
        #pragma unroll
        for (int k4 = 0; k4 < DINN / 4; ++k4) {
            const float w0 = W_in[(k4*4+0)*DINN + c];
            const float w1 = W_in[(k4*4+1)*DINN + c];
            const float w2 = W_in[(k4*4+2)*DINN + c];
            const float w3 = W_in[(k4*4+3)*DINN + c];
            float4 v0 = *(const float4*)&xt[r0 +  0][k4*4];
            float4 v1 = *(const float4*)&xt[r0 +  4][k4*4];
            float4 v2 = *(const float4*)&xt[r0 +  8][k4*4];
            float4 v3 = *(const float4*)&xt[r0 + 12][k4*4];
            a0 += v0.x*w0 + v0.y*w1 + v0.z*w2 + v0.w*w3;
            a1 += v1.x*w0 + v1.y*w1 + v1.z*w2 + v1.w*w3;
            a2 += v2.x*w0 + v2.y*w1 + v2.z*w2 + v2.w*w3;
            a3 += v3.x*w0 + v3.y*w1 + v3.z*w2 + v3.w*w3;
        }
        xp[r0 +  0][c] = a0 >= 0.f ? a0 : NEG * a0;
        xp[r0 +  4][c] = a1 >= 0.f ? a1 : NEG * a1;
        xp[r0 +  8][c] = a2 >= 0.f ? a2 : NEG * a2;
        xp[r0 + 12][c] = a3 >= 0.f ? a3 : NEG * a3;
    }
    __syncthreads();

    {
        const int c2 = tid;
        float acc[ROWS];
        const float bl = b_lstm[c2];
        #pragma unroll
        for (int r = 0; r < ROWS; ++r) acc[r] = bl;
        #pragma unroll 4
        for (int k4 = 0; k4 < DINN / 4; ++k4) {
            const float w0 = Wi[(k4*4+0)*G4 + c2];
            const float w1 = Wi[(k4*4+1)*G4 + c2];
            const float w2 = Wi[(k4*4+2)*G4 + c2];
            const float w3 = Wi[(k4*4+3)*G4 + c2];
            #pragma unroll
            for (int r = 0; r < ROWS; ++r) {
                float4 a = *(const float4*)&xp[r][k4*4];
                acc[r] += a.x*w0 + a.y*w1 + a.z*w2 + a.w*w3;
            }
        }
        // dest layout [slot][4*unit + gate]; c2 = gate*128 + unit
        const int dst = 4 * (c2 & 127) + (c2 >> 7);
        #pragma unroll
        for (int r = 0; r < ROWS; ++r) {
            const int t = t0 + r;
            if (mask[t])
                zc[(size_t)pos[t] * G4 + dst] = __float2half(acc[r]);
        }
    }
}

// ---------------------------------------------------------------- scan kernel
// 128 packed weight regs: w<g>_<p> = half2( Wh[kb][cg], Wh[kb+1][cg] ),
// kb = 64s + 2p (p in [0,32)), cg = (g<<7)|j.
#define DW(g,p)  unsigned w##g##_##p;
#define LW(g,p)  { const int kb = (s<<6) + 2*(p); const int cg = ((g)<<7)|j; \
    half2_t v_; v_[0] = (_Float16)Wh[(kb+0)*G4 + cg];                        \
    v_[1] = (_Float16)Wh[(kb+1)*G4 + cg];                                    \
    w##g##_##p = __builtin_bit_cast(unsigned, v_); }
#define PIN(g,p) asm volatile("" : "+v"(w##g##_##p));

#define BCH(u) __builtin_bit_cast(half2_t, (u))
#define DOTP(p, hu) {                          \
    const half2_t h_ = BCH(hu);                \
    p0 = FDOT2(h_, BCH(w0##_##p), p0);         \
    p1 = FDOT2(h_, BCH(w1##_##p), p1);         \
    p2 = FDOT2(h_, BCH(w2##_##p), p2);         \
    p3 = FDOT2(h_, BCH(w3##_##p), p3); }

#define FORP(M,g) M(g,0)  M(g,1)  M(g,2)  M(g,3)  M(g,4)  M(g,5)  M(g,6)  M(g,7)  \
                  M(g,8)  M(g,9)  M(g,10) M(g,11) M(g,12) M(g,13) M(g,14) M(g,15) \
                  M(g,16) M(g,17) M(g,18) M(g,19) M(g,20) M(g,21) M(g,22) M(g,23) \
                  M(g,24) M(g,25) M(g,26) M(g,27) M(g,28) M(g,29) M(g,30) M(g,31)
#define FORALL(M) FORP(M,0) FORP(M,1) FORP(M,2) FORP(M,3)

// one LSTM step: dot from hbuf[PI], gates with ZZ, publish h to hbuf[PO].
// z pre-loaded into accumulators on lane s==0 (counted once by xor1_add).
#define STEP(ZZ, PI, PO) {                                            \
    const __half2 zlo = *(const __half2*)&(ZZ).x;                     \
    const __half2 zhi = *(const __half2*)&(ZZ).y;                     \
    float p0 = (s == 0) ? __half2float(zlo.x) : 0.f;                  \
    float p1 = (s == 0) ? __half2float(zlo.y) : 0.f;                  \
    float p2 = (s == 0) ? __half2float(zhi.x) : 0.f;                  \
    float p3 = (s == 0) ? __half2float(zhi.y) : 0.f;                  \
    const uint4* hp4 = (const uint4*)&hbuf[PI][s << 6];               \
    const uint4 ha = hp4[0], hb = hp4[1], hc = hp4[2], hd = hp4[3];   \
    const uint4 he = hp4[4], hf = hp4[5], hg = hp4[6], hh = hp4[7];   \
    DOTP(0,  ha.x) DOTP(1,  ha.y) DOTP(2,  ha.z) DOTP(3,  ha.w)      \
    DOTP(4,  hb.x) DOTP(5,  hb.y) DOTP(6,  hb.z) DOTP(7,  hb.w)      \
    DOTP(8,  hc.x) DOTP(9,  hc.y) DOTP(10, hc.z) DOTP(11, hc.w)      \
    DOTP(12, hd.x) DOTP(13, hd.y) DOTP(14, hd.z) DOTP(15, hd.w)      \
    DOTP(16, he.x) DOTP(17, he.y) DOTP(18, he.z) DOTP(19, he.w)      \
    DOTP(20, hf.x) DOTP(21, hf.y) DOTP(22, hf.z) DOTP(23, hf.w)      \
    DOTP(24, hg.x) DOTP(25, hg.y) DOTP(26, hg.z) DOTP(27, hg.w)      \
    DOTP(28, hh.x) DOTP(29, hh.y) DOTP(30, hh.z) DOTP(31, hh.w)      \
    const float zi = xor1_add(p0);                                    \
    const float zf = xor1_add(p1);                                    \
    const float zg = xor1_add(p2);                                    \
    const float zo = xor1_add(p3);                                    \
    const float i_s = RCPF(1.f + __expf(-zi));                        \
    const float f_s = RCPF(1.f + __expf(-zf));                        \
    const float o_s = RCPF(1.f + __expf(-zo));                        \
    const float g_t = 1.f - 2.f * RCPF(__expf(2.f * zg) + 1.f);       \
    c_st = f_s * c_st + i_s * g_t;                                    \
    const float t_c = 1.f - 2.f * RCPF(__expf(2.f * c_st) + 1.f);     \
    h_st = o_s * t_c;                                                 \
    if (s == 0) hbuf[PO][j] = __float2half(h_st);                     \
    LDS_BARRIER();                                                    \
}

__global__ __launch_bounds__(256, 1)
__attribute__((amdgpu_waves_per_eu(1, 1)))
void scan_kernel(
    const __half* __restrict__ zc, const float* __restrict__ Wh,
    const int* __restrict__ cnt, const float* __restrict__ W_lat,
    const float* __restrict__ b_lat, float* __restrict__ out)
{
    const int n = threadIdx.x;
    const int j = n >> 1;        // hidden unit
    const int s = n & 1;         // k-half

    FORALL(DW)       // 128 packed half2 regs
    FORALL(LW)       // load + convert f32 -> f16
    FORALL(PIN)      // pin after load (kills rematerialization)

    __shared__ __half hbuf[2][HH];
    __shared__ float  hfin[HH];
    ((__half*)hbuf)[n] = __float2half(0.f);   // n<256 covers both buffers
    float c_st = 0.f, h_st = 0.f;
    __syncthreads();

    const int S = cnt[0];
    const uint2* prow = (const uint2*)zc + j;  // linear compacted stream
    // 2-deep register prefetch: z0/z1 hold rows i/i+1
    uint2 z0 = prow[0];
    uint2 z1 = prow[HH];
    prow += 2 * HH;

    int i = 0;
    for (; i + 1 < S; i += 2) {
        // issue prefetch for steps i+2, i+3 (first read ~2 step-bodies later)
        const uint2 za = prow[0];
        const uint2 zb = prow[HH];
        prow += 2 * HH;
        STEP(z0, 0, 1)     // step i   : read hbuf[0], write hbuf[1]
        STEP(z1, 1, 0)     // step i+1 : read hbuf[1], write hbuf[0]
        z0 = za;
        z1 = zb;
    }
    if (i < S) {           // odd tail
        STEP(z0, 0, 1)
    }

    // latent = h_f @ W_lat + b_lat  (fp32 final h for precision)
    if (s == 0) hfin[j] = h_st;
    __syncthreads();
    if (n < 16) {
        float acc = b_lat[n];
        #pragma unroll
        for (int k = 0; k < HH; ++k) acc += hfin[k] * W_lat[k * 16 + n];
        out[n] = acc;
    }
}

// ---------------------------------------------------------------- launcher
extern "C" void kernel_launch(void* const* d_in, const int* in_sizes, int n_in,
                              void* d_out, int out_size, void* d_ws, size_t ws_size,
                              hipStream_t stream) {
    const float* x      = (const float*)d_in[0];
    const int*   mask   = (const int*)  d_in[1];
    const float* W_in   = (const float*)d_in[2];
    const float* b_in   = (const float*)d_in[3];
    const float* Wi     = (const float*)d_in[4];
    const float* Wh     = (const float*)d_in[5];
    const float* b_lstm = (const float*)d_in[6];
    const float* W_lat  = (const float*)d_in[7];
    const float* b_lat  = (const float*)d_in[8];
    float* out = (float*)d_out;

    __half* zc  = (__half*)d_ws;                               // (TT+4) rows
    int*    pos = (int*)((char*)d_ws + (size_t)(TT + 4) * G4 * 2);
    int*    cnt = pos + TT;

    compact_kernel<<<1, CTH, 0, stream>>>(mask, pos, cnt);
    zx_kernel<<<TT / ROWS, 512, 0, stream>>>(x, W_in, b_in, Wi, b_lstm,
                                             mask, pos, zc);
    scan_kernel<<<1, 256, 0, stream>>>(zc, Wh, cnt, W_lat, b_lat, out);
}